// Round 1
// baseline (29.314 us; speedup 1.0000x reference)
//
#include <hip/hip_runtime.h>

#define BSZ 1024
#define CDIM 256
#define FEPS 1e-6f
#define NVALID 1047552.0  // B*(B-1)

// ---------------- Kernel A: per-row norms/sums + zero the accumulator -------
__global__ __launch_bounds__(256) void cl_stats_kernel(
    const float* __restrict__ X, float* __restrict__ rm, float* __restrict__ rp,
    double* __restrict__ acc)
{
    int wave = threadIdx.x >> 6;
    int lane = threadIdx.x & 63;
    int row  = blockIdx.x * 4 + wave;

    float4 v = *reinterpret_cast<const float4*>(&X[row * CDIM + lane * 4]);
    float n = v.x * v.x + v.y * v.y + v.z * v.z + v.w * v.w;
    float s = v.x + v.y + v.z + v.w;

    for (int off = 32; off; off >>= 1) {
        n += __shfl_xor(n, off);
        s += __shfl_xor(s, off);
    }
    if (lane == 0) {
        const float half_ce2 = 0.5f * (float)CDIM * FEPS * FEPS;
        rm[row] = n - 2.0f * FEPS * s + half_ce2;   // "i" (subtracted row) term
        rp[row] = n + 2.0f * FEPS * s + half_ce2;   // "j" (added row) term
    }
    if (threadIdx.x == 0 && blockIdx.x == 0) *acc = 0.0;
}

// ---------------- Kernel B: tiled pair loss (fused fp32 "GEMM" epilogue) ----
__global__ __launch_bounds__(256) void cl_pair_kernel(
    const float* __restrict__ X, const int* __restrict__ labels,
    const float* __restrict__ rm, const float* __restrict__ rp,
    double* __restrict__ acc)
{
    __shared__ float As[64][68];   // +4 pad: A reads conflict-free, B reads 2-way (free)
    __shared__ float Bs[64][68];
    __shared__ float wsum[4];

    const int t  = threadIdx.x;
    const int tr = t >> 4;         // 0..15
    const int tc = t & 15;         // 0..15
    const int rowBase = blockIdx.y * 64;
    const int colBase = blockIdx.x * 64;

    float dot[4][4];
#pragma unroll
    for (int a = 0; a < 4; ++a)
#pragma unroll
        for (int b = 0; b < 4; ++b) dot[a][b] = 0.0f;

    for (int kb = 0; kb < CDIM; kb += 64) {
        // ---- stage 64x64 chunks of A-rows and B-rows ----
#pragma unroll
        for (int l = 0; l < 4; ++l) {
            int f  = t + l * 256;      // 0..1023 float4 slots
            int r  = f >> 4;           // 0..63
            int kc = (f & 15) * 4;     // 0..60
            float4 va = *reinterpret_cast<const float4*>(&X[(rowBase + r) * CDIM + kb + kc]);
            float4 vb = *reinterpret_cast<const float4*>(&X[(colBase + r) * CDIM + kb + kc]);
            *reinterpret_cast<float4*>(&As[r][kc]) = va;
            *reinterpret_cast<float4*>(&Bs[r][kc]) = vb;
        }
        __syncthreads();

        // ---- 4x4 register-tile dot products over this K chunk ----
#pragma unroll
        for (int k4 = 0; k4 < 16; ++k4) {
            float4 a4[4], b4[4];
#pragma unroll
            for (int ii = 0; ii < 4; ++ii)
                a4[ii] = *reinterpret_cast<const float4*>(&As[tr + 16 * ii][k4 * 4]);
#pragma unroll
            for (int jj = 0; jj < 4; ++jj)
                b4[jj] = *reinterpret_cast<const float4*>(&Bs[tc + 16 * jj][k4 * 4]);
#pragma unroll
            for (int ii = 0; ii < 4; ++ii)
#pragma unroll
                for (int jj = 0; jj < 4; ++jj) {
                    float d = dot[ii][jj];
                    d = fmaf(a4[ii].x, b4[jj].x, d);
                    d = fmaf(a4[ii].y, b4[jj].y, d);
                    d = fmaf(a4[ii].z, b4[jj].z, d);
                    d = fmaf(a4[ii].w, b4[jj].w, d);
                    dot[ii][jj] = d;
                }
        }
        __syncthreads();
    }

    // ---- epilogue: per-pair loss contribution ----
    int   labI[4], labJ[4];
    float rmI[4], rpJ[4];
    int   iIdx[4], jIdx[4];
#pragma unroll
    for (int ii = 0; ii < 4; ++ii) {
        int i = rowBase + tr + 16 * ii;
        iIdx[ii] = i; labI[ii] = labels[i]; rmI[ii] = rm[i];
    }
#pragma unroll
    for (int jj = 0; jj < 4; ++jj) {
        int j = colBase + tc + 16 * jj;
        jIdx[jj] = j; labJ[jj] = labels[j]; rpJ[jj] = rp[j];
    }

    float local = 0.0f;
#pragma unroll
    for (int ii = 0; ii < 4; ++ii)
#pragma unroll
        for (int jj = 0; jj < 4; ++jj) {
            float d2 = fmaxf(rmI[ii] + rpJ[jj] - 2.0f * dot[ii][jj], 0.0f);
            float dist = sqrtf(d2);
            float m = fmaxf(1.0f - dist, 0.0f);
            float contrib = (labI[ii] == labJ[jj]) ? d2 : (m * m);
            if (iIdx[ii] != jIdx[jj]) local += contrib;
        }

    // ---- block reduce, one f64 atomic per block ----
    for (int off = 32; off; off >>= 1) local += __shfl_xor(local, off);
    if ((t & 63) == 0) wsum[t >> 6] = local;
    __syncthreads();
    if (t == 0)
        atomicAdd(acc, (double)(wsum[0] + wsum[1] + wsum[2] + wsum[3]));
}

// ---------------- Kernel C: finalize --------------------------------------
__global__ void cl_finalize_kernel(const double* __restrict__ acc,
                                   float* __restrict__ out)
{
    out[0] = (float)(*acc / NVALID);
}

extern "C" void kernel_launch(void* const* d_in, const int* in_sizes, int n_in,
                              void* d_out, int out_size, void* d_ws, size_t ws_size,
                              hipStream_t stream)
{
    const float* X      = (const float*)d_in[0];
    const int*   labels = (const int*)d_in[1];
    float*       out    = (float*)d_out;

    double* acc = (double*)d_ws;
    float*  rm  = (float*)((char*)d_ws + 16);
    float*  rp  = rm + BSZ;

    cl_stats_kernel<<<BSZ / 4, 256, 0, stream>>>(X, rm, rp, acc);
    cl_pair_kernel<<<dim3(16, 16), 256, 0, stream>>>(X, labels, rm, rp, acc);
    cl_finalize_kernel<<<1, 1, 0, stream>>>(acc, out);
}

// Round 2
// 23.961 us; speedup vs baseline: 1.2234x; 1.2234x over previous
//
#include <hip/hip_runtime.h>

#define BSZ 1024
#define CDIM 256
#define FEPS 1e-6f
#define NVALID 1047552.0  // B*(B-1)

typedef short bf16x8 __attribute__((ext_vector_type(8)));
typedef float f32x16 __attribute__((ext_vector_type(16)));

__device__ __forceinline__ unsigned short f2bf(float f) {
    unsigned u = __float_as_uint(f);
    u += 0x7FFFu + ((u >> 16) & 1u);   // round-to-nearest-even
    return (unsigned short)(u >> 16);
}

// ---- Kernel A: per-row norms/sums, fp32->bf16 convert, zero accumulators ----
__global__ __launch_bounds__(256) void cl_prep_kernel(
    const float* __restrict__ X, float* __restrict__ rm, float* __restrict__ rp,
    unsigned short* __restrict__ Xb, double* __restrict__ acc,
    unsigned* __restrict__ cnt)
{
    int wave = threadIdx.x >> 6, lane = threadIdx.x & 63;
    int row  = blockIdx.x * 4 + wave;

    float4 v = *reinterpret_cast<const float4*>(&X[row * CDIM + lane * 4]);
    ushort4 h;
    h.x = f2bf(v.x); h.y = f2bf(v.y); h.z = f2bf(v.z); h.w = f2bf(v.w);
    *reinterpret_cast<ushort4*>(&Xb[row * CDIM + lane * 4]) = h;

    float n = v.x * v.x + v.y * v.y + v.z * v.z + v.w * v.w;
    float s = v.x + v.y + v.z + v.w;
    for (int off = 32; off; off >>= 1) {
        n += __shfl_xor(n, off);
        s += __shfl_xor(s, off);
    }
    if (lane == 0) {
        const float half_ce2 = 0.5f * (float)CDIM * FEPS * FEPS;
        rm[row] = n - 2.0f * FEPS * s + half_ce2;   // subtracted-row term
        rp[row] = n + 2.0f * FEPS * s + half_ce2;   // added-row term
    }
    if (blockIdx.x == 0 && threadIdx.x == 0) { *acc = 0.0; *cnt = 0u; }
}

// ---- Kernel B: MFMA Gram tiles + fused loss epilogue + last-block finalize ----
__global__ __launch_bounds__(256, 1) void cl_pair_kernel(
    const unsigned short* __restrict__ Xb, const int* __restrict__ labels,
    const float* __restrict__ rm, const float* __restrict__ rp,
    double* __restrict__ acc, unsigned* __restrict__ cnt,
    float* __restrict__ out)
{
    __shared__ float wsum[4];

    const int t    = threadIdx.x;
    const int w    = t >> 6;          // wave 0..3 -> 2x2 grid of 32x32 tiles
    const int lane = t & 63;
    const int lr   = lane & 31;
    const int hi   = lane >> 5;

    const int rbase = blockIdx.y * 64 + (w >> 1) * 32;
    const int cbase = blockIdx.x * 64 + (w & 1) * 32;

    // gemm_bt symmetric fragment pattern: row = lane&31, k = (lane>>5)*8 (+8 per half-K)
    const unsigned short* Arow = Xb + (rbase + lr) * CDIM + hi * 8;
    const unsigned short* Brow = Xb + (cbase + lr) * CDIM + hi * 8;

    f32x16 dot = {};
#pragma unroll
    for (int s = 0; s < 16; ++s) {            // K = 256 = 16 steps of 16
        bf16x8 a = *reinterpret_cast<const bf16x8*>(Arow + s * 16);
        bf16x8 b = *reinterpret_cast<const bf16x8*>(Brow + s * 16);
        dot = __builtin_amdgcn_mfma_f32_32x32x16_bf16(a, b, dot, 0, 0, 0);
    }

    // epilogue: C/D layout col=lane&31, row=(reg&3)+8*(reg>>2)+4*(lane>>5)
    const int j    = cbase + lr;
    const float rpj = rp[j];
    const int  labj = labels[j];

    float local = 0.0f;
#pragma unroll
    for (int r = 0; r < 16; ++r) {
        int i = rbase + (r & 3) + 8 * (r >> 2) + 4 * hi;
        float d2 = fmaxf(rm[i] + rpj - 2.0f * dot[r], 0.0f);
        float dist = sqrtf(d2);
        float m = fmaxf(1.0f - dist, 0.0f);
        float c = (labels[i] == labj) ? d2 : m * m;
        if (i != j) local += c;
    }

    for (int off = 32; off; off >>= 1) local += __shfl_xor(local, off);
    if (lane == 0) wsum[w] = local;
    __syncthreads();

    if (t == 0) {
        double blocksum = (double)wsum[0] + wsum[1] + wsum[2] + wsum[3];
        atomicAdd(acc, blocksum);
        __threadfence();
        unsigned old = atomicAdd(cnt, 1u);
        if (old == 255u) {                    // last of 256 blocks
            __threadfence();
            double total = atomicAdd(acc, 0.0);   // atomic read of final sum
            out[0] = (float)(total / NVALID);
        }
    }
}

extern "C" void kernel_launch(void* const* d_in, const int* in_sizes, int n_in,
                              void* d_out, int out_size, void* d_ws, size_t ws_size,
                              hipStream_t stream)
{
    const float* X      = (const float*)d_in[0];
    const int*   labels = (const int*)d_in[1];
    float*       out    = (float*)d_out;

    char* ws = (char*)d_ws;
    double*         acc = (double*)(ws + 0);
    unsigned*       cnt = (unsigned*)(ws + 8);
    float*          rm  = (float*)(ws + 256);
    float*          rp  = (float*)(ws + 256 + 4096);
    unsigned short* Xb  = (unsigned short*)(ws + 256 + 8192 + 256);  // 16B-aligned

    cl_prep_kernel<<<BSZ / 4, 256, 0, stream>>>(X, rm, rp, Xb, acc, cnt);
    cl_pair_kernel<<<dim3(16, 16), 256, 0, stream>>>(Xb, labels, rm, rp, acc, cnt, out);
}

// Round 3
// 16.435 us; speedup vs baseline: 1.7837x; 1.4580x over previous
//
#include <hip/hip_runtime.h>
#include <hip/hip_bf16.h>

#define BSZ 1024
#define CDIM 256
#define NVALID 1047552.0   // B*(B-1)

typedef short bf16x8 __attribute__((ext_vector_type(8)));
typedef float f32x16 __attribute__((ext_vector_type(16)));

// ---- Main kernel: fused convert + norms + MFMA Gram + loss epilogue --------
// One wave per 32x32 output tile; no LDS, no syncthreads, no atomics.
__global__ __launch_bounds__(256, 1) void cl_main_kernel(
    const float* __restrict__ X, const int* __restrict__ labels,
    double* __restrict__ partials)
{
    const int t    = threadIdx.x;
    const int w    = t >> 6;          // wave 0..3 -> 2x2 grid of 32x32 tiles
    const int lane = t & 63;
    const int lr   = lane & 31;
    const int hi   = lane >> 5;

    const int rbase = blockIdx.y * 64 + (w >> 1) * 32;
    const int cbase = blockIdx.x * 64 + (w & 1) * 32;

    // MFMA bf16 32x32x16 fragment pattern: row = lane&31, k = (lane>>5)*8 (+16/step)
    const float* Ap = X + (rbase + lr) * CDIM + hi * 8;
    const float* Bp = X + (cbase + lr) * CDIM + hi * 8;

    const int labA = labels[rbase + lr];   // label of this lane's A-row
    const int labB = labels[cbase + lr];   // label of this lane's B-col

    f32x16 dot = {};
    float nA = 0.0f, nB = 0.0f;

#pragma unroll
    for (int s = 0; s < 16; ++s) {        // K = 256 = 16 steps of 16
        float4 a0 = *reinterpret_cast<const float4*>(Ap + s * 16);
        float4 a1 = *reinterpret_cast<const float4*>(Ap + s * 16 + 4);
        float4 b0 = *reinterpret_cast<const float4*>(Bp + s * 16);
        float4 b1 = *reinterpret_cast<const float4*>(Bp + s * 16 + 4);

        // fp32 row-norm partials (this lane's K-subset of its row)
        nA = fmaf(a0.x, a0.x, nA); nA = fmaf(a0.y, a0.y, nA);
        nA = fmaf(a0.z, a0.z, nA); nA = fmaf(a0.w, a0.w, nA);
        nA = fmaf(a1.x, a1.x, nA); nA = fmaf(a1.y, a1.y, nA);
        nA = fmaf(a1.z, a1.z, nA); nA = fmaf(a1.w, a1.w, nA);
        nB = fmaf(b0.x, b0.x, nB); nB = fmaf(b0.y, b0.y, nB);
        nB = fmaf(b0.z, b0.z, nB); nB = fmaf(b0.w, b0.w, nB);
        nB = fmaf(b1.x, b1.x, nB); nB = fmaf(b1.y, b1.y, nB);
        nB = fmaf(b1.z, b1.z, nB); nB = fmaf(b1.w, b1.w, nB);

        // packed RNE fp32->bf16 (static union indices -> registers)
        union { bf16x8 v; __hip_bfloat162 h[4]; } au, bu;
        au.h[0] = __float22bfloat162_rn(make_float2(a0.x, a0.y));
        au.h[1] = __float22bfloat162_rn(make_float2(a0.z, a0.w));
        au.h[2] = __float22bfloat162_rn(make_float2(a1.x, a1.y));
        au.h[3] = __float22bfloat162_rn(make_float2(a1.z, a1.w));
        bu.h[0] = __float22bfloat162_rn(make_float2(b0.x, b0.y));
        bu.h[1] = __float22bfloat162_rn(make_float2(b0.z, b0.w));
        bu.h[2] = __float22bfloat162_rn(make_float2(b1.x, b1.y));
        bu.h[3] = __float22bfloat162_rn(make_float2(b1.z, b1.w));

        dot = __builtin_amdgcn_mfma_f32_32x32x16_bf16(au.v, bu.v, dot, 0, 0, 0);
    }

    // combine the two K-half norm partials (lane x <-> lane x+32 hold halves)
    nA += __shfl_xor(nA, 32);
    nB += __shfl_xor(nB, 32);

    // epilogue: C/D layout col=lane&31, row=(r&3)+8*(r>>2)+4*(lane>>5)
    const int j = cbase + lr;
    float local = 0.0f;
#pragma unroll
    for (int r = 0; r < 16; ++r) {
        int xrow = (r & 3) + 8 * (r >> 2) + 4 * hi;   // 0..31
        int i = rbase + xrow;
        float rmI = __shfl(nA, xrow);                 // norm of A-row xrow
        int   li  = __shfl(labA, xrow);               // label of A-row xrow
        float d2 = fmaxf(rmI + nB - 2.0f * dot[r], 0.0f);
        float dist = sqrtf(d2);
        float m = fmaxf(1.0f - dist, 0.0f);
        float c = (li == labB) ? d2 : m * m;
        if (i != j) local += c;
    }

    // wave reduce -> one uncontended f64 partial per wave
    for (int off = 32; off; off >>= 1) local += __shfl_xor(local, off);
    if (lane == 0) {
        int widx = (blockIdx.y * 16 + blockIdx.x) * 4 + w;
        partials[widx] = (double)local;
    }
}

// ---- Finalize: deterministic reduction of 1024 wave partials ---------------
__global__ __launch_bounds__(256) void cl_final_kernel(
    const double* __restrict__ p, float* __restrict__ out)
{
    __shared__ double ws4[4];
    int t = threadIdx.x;
    double s = p[t] + p[t + 256] + p[t + 512] + p[t + 768];
    for (int off = 32; off; off >>= 1) s += __shfl_xor(s, off);
    if ((t & 63) == 0) ws4[t >> 6] = s;
    __syncthreads();
    if (t == 0) out[0] = (float)((ws4[0] + ws4[1] + ws4[2] + ws4[3]) / NVALID);
}

extern "C" void kernel_launch(void* const* d_in, const int* in_sizes, int n_in,
                              void* d_out, int out_size, void* d_ws, size_t ws_size,
                              hipStream_t stream)
{
    const float* X      = (const float*)d_in[0];
    const int*   labels = (const int*)d_in[1];
    float*       out    = (float*)d_out;
    double*      partials = (double*)d_ws;   // 1024 doubles

    cl_main_kernel<<<dim3(16, 16), 256, 0, stream>>>(X, labels, partials);
    cl_final_kernel<<<1, 256, 0, stream>>>(partials, out);
}